// Round 5
// baseline (193.490 us; speedup 1.0000x reference)
//
#include <hip/hip_runtime.h>
#include <math.h>

#define EPS_CLN 1e-6f

// Problem dims (fixed by the reference's setup_inputs)
constexpr int Bb = 8;
constexpr int Cc = 256;
constexpr int Tt = 8192;

// Block = 32 t x 256 ch, 128 threads (2 waves).
// tid -> t4i = tid&7 (8 float4 = 128 B contiguous per wave segment), cg = tid>>3 (16 groups x 16 ch).
// Channel reduce: in-wave shfl_xor butterfly over lane bits 3..5, then 2 KB LDS + one 32-thread pass.
constexpr int TT    = 32;           // t per block
constexpr int CPT   = 16;           // channels per thread
constexpr int NCG   = Cc / CPT;     // 16 channel groups
constexpr int NTHR  = 128;          // 2 waves
constexpr int WAVES = NTHR / 64;    // 2
constexpr int NTB   = Tt / TT;      // 256 t-blocks per b
constexpr int NBLK  = Bb * NTB;     // 2048 blocks

__global__ __launch_bounds__(NTHR, 8)
void cln_kernel(const float* __restrict__ xr_g, const float* __restrict__ xi_g,
                const float* __restrict__ wgt, const float* __restrict__ bs,
                float* __restrict__ yr_g, float* __restrict__ yi_g) {
    __shared__ float red[WAVES][5][TT];   // per-wave partials: 2*5*32*4 = 1280 B
    __shared__ float wlds[5][TT];         // mu_r, mu_i, W00, W01, W11 (640 B)

    const int tid  = threadIdx.x;
    const int lane = tid & 63;
    const int wv   = tid >> 6;
    const int t4i  = lane & 7;          // float4 slot along t (within wave)
    const int cg   = tid >> 3;          // 0..15
    const int tb   = blockIdx.x & (NTB - 1);
    const int b    = blockIdx.x >> 8;   // / NTB
    const int tl   = t4i * 4;
    const int cbase = cg * CPT;
    const size_t base = (size_t)(b * Cc + cbase) * Tt + tb * TT + tl;

    // ---- load 16 channels x 4 t x {re,im}; 128 B-line-aligned wave segments ----
    float4 xr[CPT], xi[CPT];
#pragma unroll
    for (int k = 0; k < CPT; ++k) {
        xr[k] = *(const float4*)(xr_g + base + (size_t)k * Tt);
        xi[k] = *(const float4*)(xi_g + base + (size_t)k * Tt);
    }

    // ---- per-thread partial stats over its 16 channels ----
    float4 sr = make_float4(0.f, 0.f, 0.f, 0.f);
    float4 si = sr, srr = sr, sri = sr, sii = sr;
#pragma unroll
    for (int k = 0; k < CPT; ++k) {
#define ACC1(c) { float r = xr[k].c, m = xi[k].c;          \
        sr.c += r; si.c += m;                              \
        srr.c = fmaf(r, r, srr.c);                         \
        sri.c = fmaf(r, m, sri.c);                         \
        sii.c = fmaf(m, m, sii.c); }
        ACC1(x) ACC1(y) ACC1(z) ACC1(w)
#undef ACC1
    }

    // ---- in-wave butterfly over the 8 channel groups of this wave (lane bits 3..5) ----
#define REDC(v, cc, mask) v.cc += __shfl_xor(v.cc, mask);
#define REDV(v, mask) REDC(v,x,mask) REDC(v,y,mask) REDC(v,z,mask) REDC(v,w,mask)
#define REDALL(mask) REDV(sr,mask) REDV(si,mask) REDV(srr,mask) REDV(sri,mask) REDV(sii,mask)
    REDALL(8) REDALL(16) REDALL(32)
#undef REDALL
#undef REDV
#undef REDC

    // lanes 0..7 of each wave hold the wave-total for t = lane*4 .. +3
    if (lane < 8) {
        *(float4*)&red[wv][0][tl] = sr;
        *(float4*)&red[wv][1][tl] = si;
        *(float4*)&red[wv][2][tl] = srr;
        *(float4*)&red[wv][3][tl] = sri;
        *(float4*)&red[wv][4][tl] = sii;
    }
    __syncthreads();

    // ---- final: sum the 2 wave-partials, closed-form 2x2 inverse sqrt, 1 thread per t ----
    if (tid < TT) {
        const float s0 = red[0][0][tid] + red[1][0][tid];
        const float s1 = red[0][1][tid] + red[1][1][tid];
        const float s2 = red[0][2][tid] + red[1][2][tid];
        const float s3 = red[0][3][tid] + red[1][3][tid];
        const float s4 = red[0][4][tid] + red[1][4][tid];
        const float invC = 1.0f / (float)Cc;
        const float mur = s0 * invC, mui = s1 * invC;
        // V = E[x x^T] - mu mu^T + eps I
        const float a  = fmaf(-mur, mur, s2 * invC) + EPS_CLN;
        const float bb = fmaf(-mur, mui, s3 * invC);
        const float d  = fmaf(-mui, mui, s4 * invC) + EPS_CLN;
        // V^{-1/2} = [[d+s, -b],[-b, a+s]] / (s*tau);  s=sqrt(det), tau=sqrt(tr+2s)
        const float s   = sqrtf(fmaf(-bb, bb, a * d));
        const float tau = sqrtf(a + d + 2.0f * s);
        const float inv = 1.0f / (s * tau);
        wlds[0][tid] = mur;
        wlds[1][tid] = mui;
        wlds[2][tid] = (d + s) * inv;   // W00
        wlds[3][tid] = -bb * inv;       // W01 = W10
        wlds[4][tid] = (a + s) * inv;   // W11
    }
    __syncthreads();

    // ---- apply; coalesced float4 stores (128 B wave segments) ----
    const float4 mur = *(const float4*)&wlds[0][tl];
    const float4 mui = *(const float4*)&wlds[1][tl];
    const float4 w00 = *(const float4*)&wlds[2][tl];
    const float4 w01 = *(const float4*)&wlds[3][tl];
    const float4 w11 = *(const float4*)&wlds[4][tl];

#pragma unroll
    for (int k = 0; k < CPT; ++k) {
        const int c = cbase + k;
        // weight layout (2,2,C): weight[i][j][c] -> wgt[(i*2+j)*C + c]
        const float wt00 = wgt[c];
        const float wt01 = wgt[Cc + c];
        const float wt10 = wgt[2 * Cc + c];
        const float wt11 = wgt[3 * Cc + c];
        const float b0 = bs[c];
        const float b1 = bs[Cc + c];
        float4 yr4, yi4;
#define APP1(cc) {                                         \
        float xcr = xr[k].cc - mur.cc;                     \
        float xci = xi[k].cc - mui.cc;                     \
        float zr = fmaf(xci, w01.cc, xcr * w00.cc);        \
        float zi = fmaf(xcr, w01.cc, xci * w11.cc);        \
        yr4.cc = fmaf(zr, wt00, fmaf(zi, wt10, b0));       \
        yi4.cc = fmaf(zr, wt01, fmaf(zi, wt11, b1)); }
        APP1(x) APP1(y) APP1(z) APP1(w)
#undef APP1
        *(float4*)(yr_g + base + (size_t)k * Tt) = yr4;
        *(float4*)(yi_g + base + (size_t)k * Tt) = yi4;
    }
}

extern "C" void kernel_launch(void* const* d_in, const int* in_sizes, int n_in,
                              void* d_out, int out_size, void* d_ws, size_t ws_size,
                              hipStream_t stream) {
    const float* xr  = (const float*)d_in[0];
    const float* xi  = (const float*)d_in[1];
    const float* wgt = (const float*)d_in[2];
    const float* bs  = (const float*)d_in[3];
    float* yr = (float*)d_out;
    float* yi = yr + (size_t)Bb * Cc * Tt;   // outputs concatenated flat
    cln_kernel<<<dim3(NBLK), NTHR, 0, stream>>>(xr, xi, wgt, bs, yr, yi);
}

// Round 6
// 61.066 us; speedup vs baseline: 3.1686x; 3.1686x over previous
//
#include <hip/hip_runtime.h>
#include <math.h>

#define EPS_CLN 1e-6f

// Problem dims (fixed by the reference's setup_inputs)
constexpr int Bb = 8;
constexpr int Cc = 256;
constexpr int Tt = 8192;

// Block = 32 t x 256 ch, 256 threads (4 waves), CPT=8 (R3's proven layout).
// Wave = 8 channel-groups x 8 t4-slots -> every wave segment is a full 128 B line.
// Reduce: in-wave shfl_xor butterfly (lane bits 3..5) -> 4 wave-partials in 2.5 KB LDS
// -> ONE barrier -> each thread combines partials and computes W for its 4 t's.
constexpr int TT    = 32;           // t per block
constexpr int CPT   = 8;            // channels per thread
constexpr int NTHR  = 256;          // 4 waves
constexpr int WAVES = NTHR / 64;    // 4
constexpr int NTB   = Tt / TT;      // 256 t-blocks per b
constexpr int NBLK  = Bb * NTB;     // 2048 blocks

__global__ __launch_bounds__(NTHR, 4)
void cln_kernel(const float* __restrict__ xr_g, const float* __restrict__ xi_g,
                const float* __restrict__ wgt, const float* __restrict__ bs,
                float* __restrict__ yr_g, float* __restrict__ yi_g) {
    __shared__ float red[WAVES][5][TT];   // 4*5*32*4 = 2560 B

    const int tid  = threadIdx.x;
    const int lane = tid & 63;
    const int wv   = tid >> 6;
    const int t4i  = lane & 7;          // float4 slot along t (within wave)
    const int tl   = t4i * 4;
    const int cg   = tid >> 3;          // 0..31 (global channel group)
    const int tb   = blockIdx.x & (NTB - 1);
    const int b    = blockIdx.x >> 8;   // / NTB
    const int cbase = cg * CPT;
    const size_t base = (size_t)(b * Cc + cbase) * Tt + tb * TT + tl;

    // ---- load 8 channels x 4 t x {re,im}; full-128B wave segments ----
    float4 xr[CPT], xi[CPT];
#pragma unroll
    for (int k = 0; k < CPT; ++k) {
        xr[k] = *(const float4*)(xr_g + base + (size_t)k * Tt);
        xi[k] = *(const float4*)(xi_g + base + (size_t)k * Tt);
    }

    // ---- per-thread partial stats over its 8 channels ----
    float4 sr = make_float4(0.f, 0.f, 0.f, 0.f);
    float4 si = sr, srr = sr, sri = sr, sii = sr;
#pragma unroll
    for (int k = 0; k < CPT; ++k) {
#define ACC1(c) { float r = xr[k].c, m = xi[k].c;          \
        sr.c += r; si.c += m;                              \
        srr.c = fmaf(r, r, srr.c);                         \
        sri.c = fmaf(r, m, sri.c);                         \
        sii.c = fmaf(m, m, sii.c); }
        ACC1(x) ACC1(y) ACC1(z) ACC1(w)
#undef ACC1
    }

    // ---- in-wave butterfly over this wave's 8 channel groups (lane bits 3..5) ----
#define REDC(v, cc, mask) v.cc += __shfl_xor(v.cc, mask);
#define REDV(v, mask) REDC(v,x,mask) REDC(v,y,mask) REDC(v,z,mask) REDC(v,w,mask)
#define REDALL(mask) REDV(sr,mask) REDV(si,mask) REDV(srr,mask) REDV(sri,mask) REDV(sii,mask)
    REDALL(8) REDALL(16) REDALL(32)
#undef REDALL
#undef REDV
#undef REDC

    // lanes 0..7 hold their wave's 64-channel partial for t = lane*4..+3
    if (lane < 8) {
        *(float4*)&red[wv][0][tl] = sr;
        *(float4*)&red[wv][1][tl] = si;
        *(float4*)&red[wv][2][tl] = srr;
        *(float4*)&red[wv][3][tl] = sri;
        *(float4*)&red[wv][4][tl] = sii;
    }
    __syncthreads();   // the ONLY barrier

    // ---- every thread: combine 4 wave-partials for its 4 t's (broadcast-friendly,
    //      conflict-free ds_read_b128), then closed-form W in-register ----
    float4 s0 = make_float4(0.f, 0.f, 0.f, 0.f);
    float4 s1 = s0, s2 = s0, s3 = s0, s4 = s0;
#pragma unroll
    for (int w = 0; w < WAVES; ++w) {
        const float4 p0 = *(const float4*)&red[w][0][tl];
        const float4 p1 = *(const float4*)&red[w][1][tl];
        const float4 p2 = *(const float4*)&red[w][2][tl];
        const float4 p3 = *(const float4*)&red[w][3][tl];
        const float4 p4 = *(const float4*)&red[w][4][tl];
        s0.x += p0.x; s0.y += p0.y; s0.z += p0.z; s0.w += p0.w;
        s1.x += p1.x; s1.y += p1.y; s1.z += p1.z; s1.w += p1.w;
        s2.x += p2.x; s2.y += p2.y; s2.z += p2.z; s2.w += p2.w;
        s3.x += p3.x; s3.y += p3.y; s3.z += p3.z; s3.w += p3.w;
        s4.x += p4.x; s4.y += p4.y; s4.z += p4.z; s4.w += p4.w;
    }

    const float invC = 1.0f / (float)Cc;
    float4 mur, mui, w00, w01, w11;
#define WCOMP(cc) {                                                 \
    float mr = s0.cc * invC, mi = s1.cc * invC;                     \
    float a  = fmaf(-mr, mr, s2.cc * invC) + EPS_CLN;               \
    float bv = fmaf(-mr, mi, s3.cc * invC);                         \
    float d  = fmaf(-mi, mi, s4.cc * invC) + EPS_CLN;               \
    float s   = sqrtf(fmaf(-bv, bv, a * d));                        \
    float tau = sqrtf(a + d + 2.0f * s);                            \
    float inv = 1.0f / (s * tau);                                   \
    mur.cc = mr; mui.cc = mi;                                       \
    w00.cc = (d + s) * inv; w01.cc = -bv * inv; w11.cc = (a + s) * inv; }
    WCOMP(x) WCOMP(y) WCOMP(z) WCOMP(w)
#undef WCOMP

    // ---- apply; coalesced full-line float4 stores ----
#pragma unroll
    for (int k = 0; k < CPT; ++k) {
        const int c = cbase + k;
        // weight layout (2,2,C): weight[i][j][c] -> wgt[(i*2+j)*C + c]
        const float wt00 = wgt[c];
        const float wt01 = wgt[Cc + c];
        const float wt10 = wgt[2 * Cc + c];
        const float wt11 = wgt[3 * Cc + c];
        const float b0 = bs[c];
        const float b1 = bs[Cc + c];
        float4 yr4, yi4;
#define APP1(cc) {                                         \
        float xcr = xr[k].cc - mur.cc;                     \
        float xci = xi[k].cc - mui.cc;                     \
        float zr = fmaf(xci, w01.cc, xcr * w00.cc);        \
        float zi = fmaf(xcr, w01.cc, xci * w11.cc);        \
        yr4.cc = fmaf(zr, wt00, fmaf(zi, wt10, b0));       \
        yi4.cc = fmaf(zr, wt01, fmaf(zi, wt11, b1)); }
        APP1(x) APP1(y) APP1(z) APP1(w)
#undef APP1
        *(float4*)(yr_g + base + (size_t)k * Tt) = yr4;
        *(float4*)(yi_g + base + (size_t)k * Tt) = yi4;
    }
}

extern "C" void kernel_launch(void* const* d_in, const int* in_sizes, int n_in,
                              void* d_out, int out_size, void* d_ws, size_t ws_size,
                              hipStream_t stream) {
    const float* xr  = (const float*)d_in[0];
    const float* xi  = (const float*)d_in[1];
    const float* wgt = (const float*)d_in[2];
    const float* bs  = (const float*)d_in[3];
    float* yr = (float*)d_out;
    float* yi = yr + (size_t)Bb * Cc * Tt;   // outputs concatenated flat
    cln_kernel<<<dim3(NBLK), NTHR, 0, stream>>>(xr, xi, wgt, bs, yr, yi);
}

// Round 7
// 45.363 us; speedup vs baseline: 4.2654x; 1.3462x over previous
//
#include <hip/hip_runtime.h>
#include <math.h>

#define EPS_CLN 1e-6f

// Problem dims (fixed by the reference's setup_inputs)
constexpr int Bb = 8;
constexpr int Cc = 256;
constexpr int Tt = 8192;

// R3 structure (proven best): block = 32 t x 256 ch, 256 threads.
// Thread = (channel-group cg of 8 channels) x (one float4 of t).
// NEW in R7: x values pinned in VGPRs after the stats pass (no L2 re-read),
// weight/bias loads vectorized to float4.
constexpr int TT   = 32;          // t-values per block
constexpr int CPT  = 8;           // channels per thread
constexpr int NCG  = Cc / CPT;    // 32 channel groups
constexpr int NT4  = TT / 4;      // 8 float4 slots along t
constexpr int NTHR = NCG * NT4;   // 256 threads
constexpr int NTB  = Tt / TT;     // 256 t-blocks per b

__global__ __launch_bounds__(NTHR, 2)
void cln_kernel(const float* __restrict__ xr_g, const float* __restrict__ xi_g,
                const float* __restrict__ wgt, const float* __restrict__ bs,
                float* __restrict__ yr_g, float* __restrict__ yi_g) {
    // Partial-sum scratch: [stat][channel-group][t]  (5*32*32*4 = 20 KB)
    __shared__ float red[5][NCG][TT];
    // Per-t params: raw sums -> then overwritten with mu_r, mu_i, W00, W01, W11
    __shared__ float wlds[5][TT];

    const int tid = threadIdx.x;
    const int t4i = tid & (NT4 - 1);   // which float4 along t
    const int cg  = tid >> 3;          // channel group (tid / NT4)
    const int tb  = blockIdx.x & (NTB - 1);
    const int b   = blockIdx.x >> 8;   // / NTB (=256)
    const int tl  = t4i * 4;           // local t of this thread's float4

    const int cbase = cg * CPT;
    const int base  = (b * Cc + cbase) * Tt + tb * TT + tl;

    // ---- single HBM read: 8 channels x 4 t x {re,im}, held in registers ----
    float4 xr[CPT], xi[CPT];
#pragma unroll
    for (int k = 0; k < CPT; ++k) {
        xr[k] = *(const float4*)(xr_g + base + k * Tt);
        xi[k] = *(const float4*)(xi_g + base + k * Tt);
    }

    // ---- per-thread partial stats over its 8 channels (componentwise per t) ----
    float4 sr = make_float4(0.f, 0.f, 0.f, 0.f);
    float4 si = sr, srr = sr, sri = sr, sii = sr;
#pragma unroll
    for (int k = 0; k < CPT; ++k) {
#define ACC1(c) { float r = xr[k].c, m = xi[k].c;          \
        sr.c += r; si.c += m;                              \
        srr.c = fmaf(r, r, srr.c);                         \
        sri.c = fmaf(r, m, sri.c);                         \
        sii.c = fmaf(m, m, sii.c); }
        ACC1(x) ACC1(y) ACC1(z) ACC1(w)
#undef ACC1
    }

    // ---- pin x in registers: forbid the compiler from re-loading it later ----
#pragma unroll
    for (int k = 0; k < CPT; ++k) {
        asm volatile("" : "+v"(xr[k].x), "+v"(xr[k].y), "+v"(xr[k].z), "+v"(xr[k].w),
                          "+v"(xi[k].x), "+v"(xi[k].y), "+v"(xi[k].z), "+v"(xi[k].w));
    }

    *(float4*)&red[0][cg][tl] = sr;
    *(float4*)&red[1][cg][tl] = si;
    *(float4*)&red[2][cg][tl] = srr;
    *(float4*)&red[3][cg][tl] = sri;
    *(float4*)&red[4][cg][tl] = sii;
    __syncthreads();

    // ---- parallel reduce over the 32 channel groups: 160 threads, one per (stat,t) ----
    if (tid < 5 * TT) {
        const int st = tid >> 5;       // stat 0..4
        const int t  = tid & (TT - 1); // t 0..31  -> bank = t, conflict-free
        float s = 0.f;
#pragma unroll
        for (int g = 0; g < NCG; ++g) s += red[st][g][t];
        wlds[st][t] = s;
    }
    __syncthreads();

    // ---- closed-form 2x2 inverse-sqrt whitening matrix, one thread per t ----
    if (tid < TT) {
        const float invC = 1.0f / (float)Cc;
        const float mur = wlds[0][tid] * invC, mui = wlds[1][tid] * invC;
        // V = E[x x^T] - mu mu^T + eps I
        const float a  = fmaf(-mur, mur, wlds[2][tid] * invC) + EPS_CLN;
        const float bb = fmaf(-mur, mui, wlds[3][tid] * invC);
        const float d  = fmaf(-mui, mui, wlds[4][tid] * invC) + EPS_CLN;
        // V^{-1/2} = [[d+s, -b],[-b, a+s]] / (s*tau);  s=sqrt(det), tau=sqrt(tr+2s)
        const float s   = sqrtf(fmaf(-bb, bb, a * d));
        const float tau = sqrtf(a + d + 2.0f * s);
        const float inv = 1.0f / (s * tau);
        wlds[0][tid] = mur;
        wlds[1][tid] = mui;
        wlds[2][tid] = (d + s) * inv;   // W00
        wlds[3][tid] = -bb * inv;       // W01 = W10
        wlds[4][tid] = (a + s) * inv;   // W11
    }
    __syncthreads();

    // ---- apply from pinned registers; coalesced float4 stores ----
    const float4 mur = *(const float4*)&wlds[0][tl];
    const float4 mui = *(const float4*)&wlds[1][tl];
    const float4 w00 = *(const float4*)&wlds[2][tl];
    const float4 w01 = *(const float4*)&wlds[3][tl];
    const float4 w11 = *(const float4*)&wlds[4][tl];

    // weight layout (2,2,C): weight[i][j][c] -> wgt[(i*2+j)*C + c]; bias (2,C).
    // Vectorized: 12 float4 loads replace 48 scalar dword loads.
#define APPK(cc, k, WT00, WT01, WT10, WT11, B0, B1) {      \
        float4 yr4, yi4;                                   \
        float xcr, xci, zr, zi;                            \
        xcr = xr[k].x - mur.x;  xci = xi[k].x - mui.x;     \
        zr = fmaf(xci, w01.x, xcr * w00.x);                \
        zi = fmaf(xcr, w01.x, xci * w11.x);                \
        yr4.x = fmaf(zr, WT00.cc, fmaf(zi, WT10.cc, B0.cc)); \
        yi4.x = fmaf(zr, WT01.cc, fmaf(zi, WT11.cc, B1.cc)); \
        xcr = xr[k].y - mur.y;  xci = xi[k].y - mui.y;     \
        zr = fmaf(xci, w01.y, xcr * w00.y);                \
        zi = fmaf(xcr, w01.y, xci * w11.y);                \
        yr4.y = fmaf(zr, WT00.cc, fmaf(zi, WT10.cc, B0.cc)); \
        yi4.y = fmaf(zr, WT01.cc, fmaf(zi, WT11.cc, B1.cc)); \
        xcr = xr[k].z - mur.z;  xci = xi[k].z - mui.z;     \
        zr = fmaf(xci, w01.z, xcr * w00.z);                \
        zi = fmaf(xcr, w01.z, xci * w11.z);                \
        yr4.z = fmaf(zr, WT00.cc, fmaf(zi, WT10.cc, B0.cc)); \
        yi4.z = fmaf(zr, WT01.cc, fmaf(zi, WT11.cc, B1.cc)); \
        xcr = xr[k].w - mur.w;  xci = xi[k].w - mui.w;     \
        zr = fmaf(xci, w01.w, xcr * w00.w);                \
        zi = fmaf(xcr, w01.w, xci * w11.w);                \
        yr4.w = fmaf(zr, WT00.cc, fmaf(zi, WT10.cc, B0.cc)); \
        yi4.w = fmaf(zr, WT01.cc, fmaf(zi, WT11.cc, B1.cc)); \
        *(float4*)(yr_g + base + (k) * Tt) = yr4;          \
        *(float4*)(yi_g + base + (k) * Tt) = yi4;          \
    }

#pragma unroll
    for (int k4 = 0; k4 < 2; ++k4) {
        const int c0 = cbase + k4 * 4;
        const float4 wt00v = *(const float4*)(wgt + c0);
        const float4 wt01v = *(const float4*)(wgt + Cc + c0);
        const float4 wt10v = *(const float4*)(wgt + 2 * Cc + c0);
        const float4 wt11v = *(const float4*)(wgt + 3 * Cc + c0);
        const float4 b0v   = *(const float4*)(bs + c0);
        const float4 b1v   = *(const float4*)(bs + Cc + c0);
        APPK(x, k4 * 4 + 0, wt00v, wt01v, wt10v, wt11v, b0v, b1v)
        APPK(y, k4 * 4 + 1, wt00v, wt01v, wt10v, wt11v, b0v, b1v)
        APPK(z, k4 * 4 + 2, wt00v, wt01v, wt10v, wt11v, b0v, b1v)
        APPK(w, k4 * 4 + 3, wt00v, wt01v, wt10v, wt11v, b0v, b1v)
    }
#undef APPK
}

extern "C" void kernel_launch(void* const* d_in, const int* in_sizes, int n_in,
                              void* d_out, int out_size, void* d_ws, size_t ws_size,
                              hipStream_t stream) {
    const float* xr  = (const float*)d_in[0];
    const float* xi  = (const float*)d_in[1];
    const float* wgt = (const float*)d_in[2];
    const float* bs  = (const float*)d_in[3];
    float* yr = (float*)d_out;
    float* yi = yr + (size_t)Bb * Cc * Tt;   // outputs concatenated flat
    dim3 grid(Bb * NTB);                     // 2048 blocks
    cln_kernel<<<grid, NTHR, 0, stream>>>(xr, xi, wgt, bs, yr, yi);
}